// Round 1
// baseline (125.049 us; speedup 1.0000x reference)
//
#include <hip/hip_runtime.h>

#define SEQ 2048
#define FR  133        // frame repr len
#define H0I 3
#define H1I 68
#define NOHAND -1.0f
#define BLK 1024

__global__ __launch_bounds__(BLK) void normalizer_kernel(
    const float* __restrict__ X, float* __restrict__ Out) {
    __shared__ unsigned char s_mask[SEQ];   // bit0: hand0 valid, bit1: hand1 valid
    __shared__ float s_ref[6];              // r0x r0y r0z r1x r1y r1z
    __shared__ int s_red0[16], s_red1[16];

    const int b   = blockIdx.x;
    const int tid = threadIdx.x;
    const float* xb = X   + (size_t)b * (SEQ * FR);
    float*       ob = Out + (size_t)b * (SEQ * FR);

    // ---- Phase A: per-frame validity + last-valid-frame reduction ----
    int m0 = -1, m1 = -1;
    for (int t = tid; t < SEQ; t += BLK) {
        float v0 = xb[(size_t)t * FR + H0I];
        float v1 = xb[(size_t)t * FR + H1I];
        int b0 = (v0 != NOHAND);
        int b1 = (v1 != NOHAND);
        s_mask[t] = (unsigned char)(b0 | (b1 << 1));
        if (b0) m0 = t;          // t strictly increases across iterations
        if (b1) m1 = t;
    }
    // wave (64-lane) max reduce
    #pragma unroll
    for (int off = 32; off > 0; off >>= 1) {
        m0 = max(m0, __shfl_down(m0, off, 64));
        m1 = max(m1, __shfl_down(m1, off, 64));
    }
    int wave = tid >> 6, lane = tid & 63;
    if (lane == 0) { s_red0[wave] = m0; s_red1[wave] = m1; }
    __syncthreads();
    if (tid == 0) {
        int a0 = -1, a1 = -1;
        #pragma unroll
        for (int w = 0; w < BLK / 64; ++w) {
            a0 = max(a0, s_red0[w]);
            a1 = max(a1, s_red1[w]);
        }
        int l0 = a0 < 0 ? 0 : a0;   // jnp.maximum(..., 0); mask kills it if invalid
        int l1 = a1 < 0 ? 0 : a1;
        s_ref[0] = xb[(size_t)l0 * FR + 5];
        s_ref[1] = xb[(size_t)l0 * FR + 26];
        s_ref[2] = xb[(size_t)l0 * FR + 47];
        s_ref[3] = xb[(size_t)l1 * FR + 70];
        s_ref[4] = xb[(size_t)l1 * FR + 91];
        s_ref[5] = xb[(size_t)l1 * FR + 112];
    }
    __syncthreads();
    const float r0x = s_ref[0], r0y = s_ref[1], r0z = s_ref[2];
    const float r1x = s_ref[3], r1y = s_ref[4], r1z = s_ref[5];

    // ---- Phase B: stream the slab as float4 ----
    const int NV = (SEQ * FR) / 4;              // 68096, exact
    const float4* xv = (const float4*)xb;
    float4*       ov = (float4*)ob;
    for (int i = tid; i < NV; i += BLK) {
        float4 v = xv[i];
        int e     = i * 4;
        int frame = (int)((unsigned)e / 133u);  // magic-mul div
        int f0    = e - frame * 133;
        float vals[4] = {v.x, v.y, v.z, v.w};
        #pragma unroll
        for (int j = 0; j < 4; ++j) {
            int f = f0 + j;
            int fr = frame;
            if (f >= FR) { f -= FR; fr += 1; }
            int mk = s_mask[fr];
            float sub = 0.f;
            if (f >= 5 && f < 68) {
                if (mk & 1) {
                    int k = (f >= 26) + (f >= 47);
                    sub = (k == 0) ? r0x : ((k == 1) ? r0y : r0z);
                }
            } else if (f >= 70) {
                if (mk & 2) {
                    int k = (f >= 91) + (f >= 112);
                    sub = (k == 0) ? r1x : ((k == 1) ? r1y : r1z);
                }
            }
            vals[j] -= sub;
        }
        float4 o; o.x = vals[0]; o.y = vals[1]; o.z = vals[2]; o.w = vals[3];
        ov[i] = o;
    }
}

extern "C" void kernel_launch(void* const* d_in, const int* in_sizes, int n_in,
                              void* d_out, int out_size, void* d_ws, size_t ws_size,
                              hipStream_t stream) {
    const float* X = (const float*)d_in[0];
    float* Out     = (float*)d_out;
    int nB = in_sizes[0] / (SEQ * FR);          // 256
    normalizer_kernel<<<nB, BLK, 0, stream>>>(X, Out);
}